// Round 4
// baseline (1219.095 us; speedup 1.0000x reference)
//
#include <hip/hip_runtime.h>
#include <hip/hip_bf16.h>

#define B_DIM 1024
#define H_DIM 2048
#define V_DIM 8192
#define L_DIM 8

typedef __attribute__((ext_vector_type(8))) __bf16 bf16x8;
typedef __attribute__((ext_vector_type(4))) __bf16 bf16x4;
typedef __attribute__((ext_vector_type(4))) float f32x4;
typedef unsigned short u16;

#define MFMA16(a, b, c) __builtin_amdgcn_mfma_f32_16x16x32_bf16((a), (b), (c), 0, 0, 0)

// ---------- prep (one dispatch): hh fp32 [L][K][N] -> hhT bf16 [L][N][K],
// plus state fp32 -> bf16 (A operand for layer 0) in the tail blocks ----------
__global__ __launch_bounds__(256) void rnn_prep(
    const float* __restrict__ hh, __bf16* __restrict__ hhT,
    const float4* __restrict__ state, bf16x4* __restrict__ stateB) {
  int bid = blockIdx.x;
  if (bid >= 8192) {
    // state convert: 2048 blocks x 256 threads x 1 float4
    int i = (bid - 8192) * 256 + threadIdx.x;
    float4 v = state[i];
    bf16x4 o;
    o.x = (__bf16)v.x; o.y = (__bf16)v.y; o.z = (__bf16)v.z; o.w = (__bf16)v.w;
    stateB[i] = o;
    return;
  }
  int l = bid >> 10;
  int t = bid & 1023;
  int k0 = (t >> 5) << 6;
  int n0 = (t & 31) << 6;
  __shared__ __bf16 tile[64][67];
  int tid = threadIdx.x;
  const float* hh_l = hh + ((size_t)l << 22);
  __bf16* hhT_l = hhT + ((size_t)l << 22);
  {
    int r = tid >> 2;               // 0..63
    int c = (tid & 3) << 4;         // 0,16,32,48
    const float4* src = (const float4*)(hh_l + (size_t)(k0 + r) * H_DIM + n0 + c);
#pragma unroll
    for (int q = 0; q < 4; q++) {
      float4 v = src[q];
      tile[r][c + q * 4 + 0] = (__bf16)v.x;
      tile[r][c + q * 4 + 1] = (__bf16)v.y;
      tile[r][c + q * 4 + 2] = (__bf16)v.z;
      tile[r][c + q * 4 + 3] = (__bf16)v.w;
    }
  }
  __syncthreads();
  {
    int n = tid >> 2;               // 0..63
    int kq = (tid & 3) << 4;        // 0,16,32,48
    alignas(16) u16 tmp[16];
#pragma unroll
    for (int j = 0; j < 16; j++) {
      __bf16 b = tile[kq + j][n];
      tmp[j] = *(const u16*)&b;
    }
    uint4* dst = (uint4*)(hhT_l + (size_t)(n0 + n) * H_DIM + k0 + kq);
    dst[0] = *(uint4*)(tmp);
    dst[1] = *(uint4*)(tmp + 8);
  }
}

// ---------- per-layer fused GEMM + gather + tanh, NO LDS / NO barriers ----------
// C[b][h] = tanh(S[b][h] + (A @ hh_l)[b][h] * ih_l[token[b]][h])
// Every MFMA fragment is 16 contiguous bytes (A and hhT are both k-contig),
// loaded straight global->VGPR (global_load_dwordx4). Register double-buffer
// with one-K-tile lookahead; the compiler emits fine-grained per-register
// s_waitcnt vmcnt(N) (no LDS aliasing forces a vmcnt(0) drain), and the 8
// independent waves/CU self-pace with no barrier coupling.
__global__ __launch_bounds__(256) void rnn_layer_direct(
    const __bf16* __restrict__ A, const __bf16* __restrict__ Bt,
    const float* __restrict__ S, const float* __restrict__ ih_l,
    const int* __restrict__ token,
    float* __restrict__ OutF, __bf16* __restrict__ OutB) {
  constexpr int K = H_DIM;
  constexpr int NT = K / 64;       // 32 K-tiles of 64

  // XCD swizzle: the 16 m-blocks sharing an n-column land on one XCD
  int bid = blockIdx.x;
  int x = bid & 7;
  int rest = bid >> 3;
  int mi = rest & 15;
  int ni = (rest >> 4) * 8 + x;
  int bm0 = mi * 64;
  int bn0 = ni * 64;

  int tid = threadIdx.x;
  int w = tid >> 6;
  int lane = tid & 63;
  int wm = (w >> 1) * 32;
  int wn = (w & 1) * 32;
  int col = lane & 15;
  int quad = lane >> 4;

  // A-frag: lane holds A[m = base+col][k = kt*64 + ks*32 + quad*8 + j]
  // B-frag: lane holds Bt[n = base+col][same k]  (both 16B contiguous)
  const __bf16* pa0 = A + (size_t)(bm0 + wm + col) * K + quad * 8;
  const __bf16* pa1 = pa0 + (size_t)16 * K;
  const __bf16* pb0 = Bt + (size_t)(bn0 + wn + col) * K + quad * 8;
  const __bf16* pb1 = pb0 + (size_t)16 * K;

  f32x4 acc[2][2] = {};
  bf16x8 fa[2][2][2];              // [buf][ks][frag]
  bf16x8 fb[2][2][2];

  auto loadT = [&](int buf, int kt) {
    int o0 = kt * 64;
#pragma unroll
    for (int ks = 0; ks < 2; ks++) {
      int o = o0 + ks * 32;
      fa[buf][ks][0] = *(const bf16x8*)(pa0 + o);
      fa[buf][ks][1] = *(const bf16x8*)(pa1 + o);
      fb[buf][ks][0] = *(const bf16x8*)(pb0 + o);
      fb[buf][ks][1] = *(const bf16x8*)(pb1 + o);
    }
  };
  auto comp = [&](int buf) {
#pragma unroll
    for (int ks = 0; ks < 2; ks++) {
      acc[0][0] = MFMA16(fa[buf][ks][0], fb[buf][ks][0], acc[0][0]);
      acc[0][1] = MFMA16(fa[buf][ks][0], fb[buf][ks][1], acc[0][1]);
      acc[1][0] = MFMA16(fa[buf][ks][1], fb[buf][ks][0], acc[1][0]);
      acc[1][1] = MFMA16(fa[buf][ks][1], fb[buf][ks][1], acc[1][1]);
    }
  };

  loadT(0, 0);
  for (int kt = 0; kt < NT; kt += 2) {
    loadT(1, kt + 1);              // next tile in flight while computing kt
    comp(0);
    if (kt + 2 < NT) loadT(0, kt + 2);
    comp(1);
  }

  // epilogue: C/D layout col=lane&15, row=quad*4+reg (verified)
#pragma unroll
  for (int mt = 0; mt < 2; mt++) {
#pragma unroll
    for (int reg = 0; reg < 4; reg++) {
      int b = bm0 + wm + mt * 16 + quad * 4 + reg;
      int tok = token[b];
      const float* ihrow = ih_l + (size_t)tok * H_DIM;
      size_t rowoff = (size_t)b * H_DIM;
#pragma unroll
      for (int nt = 0; nt < 2; nt++) {
        int h = bn0 + wn + nt * 16 + col;
        float g = ihrow[h];
        float sv = S[rowoff + h];
        float v = tanhf(fmaf(acc[mt][nt][reg], g, sv));
        OutF[rowoff + h] = v;
        OutB[rowoff + h] = (__bf16)v;
      }
    }
  }
}

extern "C" void kernel_launch(void* const* d_in, const int* in_sizes, int n_in,
                              void* d_out, int out_size, void* d_ws, size_t ws_size,
                              hipStream_t stream) {
  const float* state = (const float*)d_in[0];
  const int* token = (const int*)d_in[1];
  const float* ih = (const float*)d_in[2];
  const float* hh = (const float*)d_in[3];

  // ws layout (88 MiB used):
  char* ws = (char*)d_ws;
  __bf16* hhT = (__bf16*)ws;                    // 8*2048*2048*2 = 67108864 B
  float* F0 = (float*)(ws + 67108864);          // 8388608 B
  float* F1 = (float*)(ws + 75497472);          // 8388608 B
  __bf16* Sb0 = (__bf16*)(ws + 83886080);       // 4194304 B
  __bf16* Sb1 = (__bf16*)(ws + 88080384);       // 4194304 B

  // weight transpose (8192 blocks) + state convert (2048 blocks), one dispatch
  rnn_prep<<<10240, 256, 0, stream>>>(hh, hhT, (const float4*)state, (bf16x4*)Sb0);

  const float* Sprev = state;                   // fp32 residual
  for (int l = 0; l < L_DIM; l++) {
    const __bf16* hhT_l = hhT + ((size_t)l << 22);
    const float* ih_l = ih + ((size_t)l << 24);
    const __bf16* Acur = (l & 1) ? Sb1 : Sb0;
    __bf16* outB = (l & 1) ? Sb0 : Sb1;
    float* outF = (l == L_DIM - 1) ? (float*)d_out : ((l & 1) ? F1 : F0);
    rnn_layer_direct<<<512, 256, 0, stream>>>(Acur, hhT_l, Sprev, ih_l, token, outF, outB);
    Sprev = outF;
  }
}